// Round 5
// baseline (133.050 us; speedup 1.0000x reference)
//
#include <hip/hip_runtime.h>

typedef __attribute__((ext_vector_type(4))) float f32x4;

#define NLVL 16
#define NPTS_PER_BLOCK 256

// Per-level constants from the reference's _level_params() (f64 math -> f32).
constexpr float SCALEC[NLVL] = {
    15.0f, 19.15873679831797f, 24.39841683149119f, 31.0f,
    39.31747359663594f, 49.79683366298238f, 63.0f, 79.63494719327189f,
    100.59366732596477f, 127.0f, 160.26989438654376f, 202.18733465192954f,
    255.0f, 321.5397887730875f, 405.3746693038591f, 511.0f
};
constexpr int RESC[NLVL] = {
    16, 21, 26, 32, 41, 51, 64, 81, 102, 128, 162, 204, 256, 323, 407, 512
};
constexpr int OFFC[NLVL] = {
    0, 4096, 13360, 30936, 63704, 132632, 265288, 527432,
    1051720, 1576008, 2100296, 2624584, 3148872, 3673160, 4197448, 4721736
};
// Levels 0..6: lin < res^3 <= hsize -> modulo is a no-op.
// Levels 7..15: hsize == 2^19      -> lin & 0x7FFFF; x-pair (e0,e0+1) wraps
// when e0 == 0x7FFFF -> fixed at ACC time via cndmask with uniform tab[off].
constexpr int HMASK = 0x7FFFF;

// ISSUE: compute indices and fire 4x 16-B gathers via inline asm. The
// compiler does NOT track vmcnt for asm loads, so no auto s_waitcnt is
// inserted -- completion is handled by the explicit counted waits below.
template<int L>
__device__ __forceinline__ void level_issue(float x, float y, float z,
                                            const float* __restrict__ emb,
                                            f32x4& q0, f32x4& q1,
                                            f32x4& q2, f32x4& q3,
                                            int& wmask)
{
    constexpr float s = SCALEC[L];
    constexpr int   r = RESC[L];
    constexpr int   off = OFFC[L];

    const float px = x * s, py = y * s, pz = z * s;
    const int lin = (int)floorf(px) + r * (int)floorf(py) + r * r * (int)floorf(pz);

    int i0 = lin, i1 = lin + r, i2 = lin + r * r, i3 = lin + r * r + r;
    if constexpr (L >= 7) {
        i0 &= HMASK; i1 &= HMASK; i2 &= HMASK; i3 &= HMASK;
        wmask = (i0 == HMASK ? 1 : 0) | (i1 == HMASK ? 2 : 0)
              | (i2 == HMASK ? 4 : 0) | (i3 == HMASK ? 8 : 0);
    } else {
        wmask = 0;
    }
    const float* p0 = emb + 2 * (off + i0);
    const float* p1 = emb + 2 * (off + i1);
    const float* p2 = emb + 2 * (off + i2);
    const float* p3 = emb + 2 * (off + i3);
    asm volatile("global_load_dwordx4 %0, %1, off" : "=v"(q0) : "v"(p0));
    asm volatile("global_load_dwordx4 %0, %1, off" : "=v"(q1) : "v"(p1));
    asm volatile("global_load_dwordx4 %0, %1, off" : "=v"(q2) : "v"(p2));
    asm volatile("global_load_dwordx4 %0, %1, off" : "=v"(q3) : "v"(p3));
}

// ACC: recompute fracs, apply rare-wrap cndmask fix, trilinear-accumulate,
// fuse into MLP layer 0 (rows 2L,2L+1 of W0; uniform addrs -> SGPR stream).
template<int L>
__device__ __forceinline__ void level_accum(float x, float y, float z,
                                            const float* __restrict__ emb,
                                            f32x4 q0, f32x4 q1,
                                            f32x4 q2, f32x4 q3,
                                            int wmask,
                                            float* __restrict__ h0,
                                            const float* __restrict__ W0)
{
    constexpr float s = SCALEC[L];
    constexpr int   off = OFFC[L];

    const float px = x * s, py = y * s, pz = z * s;
    const float tx = px - floorf(px), ty = py - floorf(py), tz = pz - floorf(pz);

    if constexpr (L >= 7) {
        const float f0x = emb[2 * off], f0y = emb[2 * off + 1];  // uniform s_load
        q0.z = (wmask & 1) ? f0x : q0.z;  q0.w = (wmask & 1) ? f0y : q0.w;
        q1.z = (wmask & 2) ? f0x : q1.z;  q1.w = (wmask & 2) ? f0y : q1.w;
        q2.z = (wmask & 4) ? f0x : q2.z;  q2.w = (wmask & 4) ? f0y : q2.w;
        q3.z = (wmask & 8) ? f0x : q3.z;  q3.w = (wmask & 8) ? f0y : q3.w;
    }

    const float wx1 = tx, wx0 = 1.0f - tx;
    const float wy1 = ty, wy0 = 1.0f - ty;
    const float wz1 = tz, wz0 = 1.0f - tz;
    const float w00 = wy0 * wz0, w10 = wy1 * wz0;
    const float w01 = wy0 * wz1, w11 = wy1 * wz1;
    float a0 = 0.0f, a1 = 0.0f;
    a0 = fmaf(w00 * wx0, q0.x, a0); a1 = fmaf(w00 * wx0, q0.y, a1);
    a0 = fmaf(w00 * wx1, q0.z, a0); a1 = fmaf(w00 * wx1, q0.w, a1);
    a0 = fmaf(w10 * wx0, q1.x, a0); a1 = fmaf(w10 * wx0, q1.y, a1);
    a0 = fmaf(w10 * wx1, q1.z, a0); a1 = fmaf(w10 * wx1, q1.w, a1);
    a0 = fmaf(w01 * wx0, q2.x, a0); a1 = fmaf(w01 * wx0, q2.y, a1);
    a0 = fmaf(w01 * wx1, q2.z, a0); a1 = fmaf(w01 * wx1, q2.w, a1);
    a0 = fmaf(w11 * wx0, q3.x, a0); a1 = fmaf(w11 * wx0, q3.y, a1);
    a0 = fmaf(w11 * wx1, q3.z, a0); a1 = fmaf(w11 * wx1, q3.w, a1);

#pragma unroll
    for (int j = 0; j < 32; ++j)
        h0[j] = fmaf(a0, W0[(2 * L + 0) * 32 + j], h0[j]);
#pragma unroll
    for (int j = 0; j < 32; ++j)
        h0[j] = fmaf(a1, W0[(2 * L + 1) * 32 + j], h0[j]);
}

__global__ __launch_bounds__(NPTS_PER_BLOCK, 4)   // cap VGPR at 128 (4 waves/SIMD)
void hashgrid_mlp_kernel(const float* __restrict__ coords,   // [N,3]
                         const float* __restrict__ emb,      // [total,2]
                         const float* __restrict__ W0,       // [32,32]
                         const float* __restrict__ b0,       // [32]
                         const float* __restrict__ W1,       // [32,32]
                         const float* __restrict__ b1,       // [32]
                         const float* __restrict__ W2,       // [32,1]
                         const float* __restrict__ b2,       // [1]
                         float* __restrict__ out,            // [N]
                         int n)
{
    const int tid = blockIdx.x * blockDim.x + threadIdx.x;
    if (tid >= n) return;

    const float x = (coords[tid * 3 + 0] + 1.0f) * 0.5f;
    const float y = (coords[tid * 3 + 1] + 1.0f) * 0.5f;
    const float z = (coords[tid * 3 + 2] + 1.0f) * 0.5f;

    float h0[32];
#pragma unroll
    for (int j = 0; j < 32; ++j) h0[j] = b0[j];

    // Depth-4 pipeline ENFORCED via asm: 16 gathers in flight steady-state.
    // Counted waits: 12,12,...,12 then 8,4,0 at the tail (never early-drain).
    f32x4 a0, a1, a2, a3; int am;
    f32x4 b0r, b1r, b2r, b3r; int bm;
    f32x4 c0, c1, c2, c3; int cm;
    f32x4 d0, d1, d2, d3; int dm;

#define ISS_A(L) level_issue<L>(x, y, z, emb, a0, a1, a2, a3, am);
#define ISS_B(L) level_issue<L>(x, y, z, emb, b0r, b1r, b2r, b3r, bm);
#define ISS_C(L) level_issue<L>(x, y, z, emb, c0, c1, c2, c3, cm);
#define ISS_D(L) level_issue<L>(x, y, z, emb, d0, d1, d2, d3, dm);
#define ACC_A(L) level_accum<L>(x, y, z, emb, a0, a1, a2, a3, am, h0, W0);
#define ACC_B(L) level_accum<L>(x, y, z, emb, b0r, b1r, b2r, b3r, bm, h0, W0);
#define ACC_C(L) level_accum<L>(x, y, z, emb, c0, c1, c2, c3, cm, h0, W0);
#define ACC_D(L) level_accum<L>(x, y, z, emb, d0, d1, d2, d3, dm, h0, W0);
#define VMWAIT(N) asm volatile("s_waitcnt vmcnt(" #N ")" ::: "memory"); \
                  __builtin_amdgcn_sched_barrier(0);

    ISS_A(0) ISS_B(1) ISS_C(2) ISS_D(3)
    VMWAIT(12) ACC_A(0)  ISS_A(4)
    VMWAIT(12) ACC_B(1)  ISS_B(5)
    VMWAIT(12) ACC_C(2)  ISS_C(6)
    VMWAIT(12) ACC_D(3)  ISS_D(7)
    VMWAIT(12) ACC_A(4)  ISS_A(8)
    VMWAIT(12) ACC_B(5)  ISS_B(9)
    VMWAIT(12) ACC_C(6)  ISS_C(10)
    VMWAIT(12) ACC_D(7)  ISS_D(11)
    VMWAIT(12) ACC_A(8)  ISS_A(12)
    VMWAIT(12) ACC_B(9)  ISS_B(13)
    VMWAIT(12) ACC_C(10) ISS_C(14)
    VMWAIT(12) ACC_D(11) ISS_D(15)
    VMWAIT(12) ACC_A(12)
    VMWAIT(8)  ACC_B(13)
    VMWAIT(4)  ACC_C(14)
    VMWAIT(0)  ACC_D(15)

#undef ISS_A
#undef ISS_B
#undef ISS_C
#undef ISS_D
#undef ACC_A
#undef ACC_B
#undef ACC_C
#undef ACC_D
#undef VMWAIT

#pragma unroll
    for (int j = 0; j < 32; ++j) h0[j] = (h0[j] >= 0.0f) ? h0[j] : 0.01f * h0[j];

    float h1[32];
#pragma unroll
    for (int j = 0; j < 32; ++j) h1[j] = b1[j];
#pragma unroll
    for (int i = 0; i < 32; ++i) {
        const float e = h0[i];
#pragma unroll
        for (int j = 0; j < 32; ++j) h1[j] = fmaf(e, W1[i * 32 + j], h1[j]);
    }
#pragma unroll
    for (int j = 0; j < 32; ++j) h1[j] = (h1[j] >= 0.0f) ? h1[j] : 0.01f * h1[j];

    float acc = b2[0];
#pragma unroll
    for (int j = 0; j < 32; ++j) acc = fmaf(h1[j], W2[j], acc);

    out[tid] = acc;
}

extern "C" void kernel_launch(void* const* d_in, const int* in_sizes, int n_in,
                              void* d_out, int out_size, void* d_ws, size_t ws_size,
                              hipStream_t stream) {
    const float* coords = (const float*)d_in[0];   // [N,1,3]
    const float* emb    = (const float*)d_in[1];   // [total,1,2]
    const float* W0     = (const float*)d_in[2];
    const float* b0     = (const float*)d_in[3];
    const float* W1     = (const float*)d_in[4];
    const float* b1     = (const float*)d_in[5];
    const float* W2     = (const float*)d_in[6];
    const float* b2     = (const float*)d_in[7];
    float* out = (float*)d_out;

    const int n = in_sizes[0] / 3;   // 262144
    const int blocks = (n + NPTS_PER_BLOCK - 1) / NPTS_PER_BLOCK;
    hashgrid_mlp_kernel<<<blocks, NPTS_PER_BLOCK, 0, stream>>>(
        coords, emb, W0, b0, W1, b1, W2, b2, out, n);
}